// Round 8
// baseline (287.223 us; speedup 1.0000x reference)
//
#include <hip/hip_runtime.h>
#include <math.h>

#define B_  2
#define T_  2048
#define C_  1024
#define H_  16
#define HD_ 64
#define FF_ 2048
#define EPS_ 1.1920929e-07f

typedef __attribute__((ext_vector_type(8))) short short8;
typedef __attribute__((ext_vector_type(4))) float f32x4;
typedef __attribute__((ext_vector_type(16))) float f32x16;
typedef __attribute__((ext_vector_type(2))) __bf16 bf16x2v;
typedef __attribute__((ext_vector_type(4))) unsigned uint4v;

__device__ __forceinline__ unsigned short f2bf(float f) {
    unsigned u = __float_as_uint(f);
    u += 0x7fffu + ((u >> 16) & 1u);          // round-to-nearest-even
    return (unsigned short)(u >> 16);
}
__device__ __forceinline__ float bf2f(unsigned short u) {
    return __uint_as_float(((unsigned)u) << 16);
}
// packed pair convert -> v_cvt_pk_bf16_f32 (RNE, one instr per 2 floats)
__device__ __forceinline__ unsigned pk2bf(float a, float b) {
    bf16x2v v;
    v[0] = (__bf16)a;
    v[1] = (__bf16)b;
    return __builtin_bit_cast(unsigned, v);
}

// ---------------- prep: weight fp32->bf16 convert + rmsnorm1, one dispatch ----------------
__global__ void prep_kernel(const float* __restrict__ wq, const float* __restrict__ wk,
                            const float* __restrict__ wv, const float* __restrict__ wp,
                            const float* __restrict__ w1, const float* __restrict__ w2,
                            unsigned short* __restrict__ wb,
                            const float* __restrict__ x, const float* __restrict__ g,
                            unsigned short* __restrict__ y) {
    int tid = threadIdx.x;
    if (blockIdx.x < 8192) {
        size_t i = ((size_t)blockIdx.x * 256 + tid) * 4;
        const float* src; size_t off = i;
        if      (i < 1048576u)  { src = wq; }
        else if (i < 2097152u)  { src = wk; off = i - 1048576u; }
        else if (i < 3145728u)  { src = wv; off = i - 2097152u; }
        else if (i < 4194304u)  { src = wp; off = i - 3145728u; }
        else if (i < 6291456u)  { src = w1; off = i - 4194304u; }
        else                    { src = w2; off = i - 6291456u; }
        float4 v4 = *(const float4*)(src + off);
        ushort4 o4;
        o4.x = f2bf(v4.x); o4.y = f2bf(v4.y); o4.z = f2bf(v4.z); o4.w = f2bf(v4.w);
        *(ushort4*)(wb + i) = o4;
    } else {
        int row = blockIdx.x - 8192;
        const float4* xr = (const float4*)(x + (size_t)row * C_);
        float4 xv = xr[tid];
        float ss = xv.x * xv.x + xv.y * xv.y + xv.z * xv.z + xv.w * xv.w;
        #pragma unroll
        for (int m = 32; m >= 1; m >>= 1) ss += __shfl_xor(ss, m, 64);
        __shared__ float sred[4];
        if ((tid & 63) == 0) sred[tid >> 6] = ss;
        __syncthreads();
        float tot = sred[0] + sred[1] + sred[2] + sred[3];
        float r = rsqrtf(tot * (1.0f / C_) + EPS_);
        float4 gv = ((const float4*)g)[tid];
        ushort4 o;
        o.x = f2bf(xv.x * r * gv.x);
        o.y = f2bf(xv.y * r * gv.y);
        o.z = f2bf(xv.z * r * gv.z);
        o.w = f2bf(xv.w * r * gv.w);
        *((ushort4*)(y + (size_t)row * C_) + tid) = o;
    }
}

// ---------------- RMSNorm (fp32 in, bf16 out) ----------------
__global__ void rmsnorm_bf16_kernel(const float* __restrict__ x, const float* __restrict__ g,
                                    unsigned short* __restrict__ y) {
    int row = blockIdx.x;
    int tid = threadIdx.x;
    const float4* xr = (const float4*)(x + (size_t)row * C_);
    float4 xv = xr[tid];
    float ss = xv.x * xv.x + xv.y * xv.y + xv.z * xv.z + xv.w * xv.w;
    #pragma unroll
    for (int m = 32; m >= 1; m >>= 1) ss += __shfl_xor(ss, m, 64);
    __shared__ float sred[4];
    if ((tid & 63) == 0) sred[tid >> 6] = ss;
    __syncthreads();
    float tot = sred[0] + sred[1] + sred[2] + sred[3];
    float r = rsqrtf(tot * (1.0f / C_) + EPS_);
    float4 gv = ((const float4*)g)[tid];
    ushort4 o;
    o.x = f2bf(xv.x * r * gv.x);
    o.y = f2bf(xv.y * r * gv.y);
    o.z = f2bf(xv.z * r * gv.z);
    o.w = f2bf(xv.w * r * gv.w);
    *((ushort4*)(y + (size_t)row * C_) + tid) = o;
}

// ---------------- bf16 MFMA GEMM, TM x 128 tile, BK=64 ----------------
// LDS layout: two BK=32 sub-tiles [kh][rows][32] for A and B.
// ROUTE==1 (QKV, N=3072): n-zone 0 -> q (x0.125*log2e, exp2 softmax), zone 1 -> k,
// zone 2 -> vT [b][h][d][t].
template <int TM, int ACT, bool BIAS, bool RES, bool OBF16, int ROUTE>
__global__ __launch_bounds__(256) void mfma_gemm(
        const unsigned short* __restrict__ A, const unsigned short* __restrict__ W,
        const float* __restrict__ bias, const float* __restrict__ resid,
        void* __restrict__ O0, void* __restrict__ O1, void* __restrict__ O2,
        int M, int N, int K) {
    constexpr int ACH = TM / 8;           // A chunks (TM rows * 64 k * 2B / 1KB)
    constexpr int NCH = (ACH + 16) / 4;   // chunks per wave
    constexpr int MI  = TM / 32;          // m-frags per wave
    __shared__ short As[2 * TM * 32];
    __shared__ short Bs[2 * 128 * 32];
    const int tid  = threadIdx.x;
    const int w    = tid >> 6, lane = tid & 63;
    const int tileN = blockIdx.x * 128, tileM = blockIdx.y * TM;

    const unsigned short* gsrc[NCH];
    short* ldst[NCH];
    #pragma unroll
    for (int i2 = 0; i2 < NCH; ++i2) {
        int c = w * NCH + i2;
        if (c < ACH) {
            int kh = c / (ACH / 2), lc = c % (ACH / 2);
            gsrc[i2] = A + (size_t)(tileM + lc * 16 + (lane >> 2)) * K + kh * 32 + (lane & 3) * 8;
            ldst[i2] = As + c * 512;
        } else {
            int c2 = c - ACH;
            int kh = c2 >> 3, lc = c2 & 7;
            gsrc[i2] = W + (size_t)(tileN + lc * 16 + (lane >> 2)) * K + kh * 32 + (lane & 3) * 8;
            ldst[i2] = Bs + c2 * 512;
        }
    }

    f32x4 acc[MI][4];
    const f32x4 zed = {0.f, 0.f, 0.f, 0.f};
    #pragma unroll
    for (int i = 0; i < MI; ++i)
        #pragma unroll
        for (int j = 0; j < 4; ++j) acc[i][j] = zed;

    const int wm = (w >> 1) * (TM / 2), wn = (w & 1) * 64;
    const int frow = lane & 15, koff = (lane >> 4) * 8;

    for (int k0 = 0; k0 < K; k0 += 64) {
        #pragma unroll
        for (int i2 = 0; i2 < NCH; ++i2)
            __builtin_amdgcn_global_load_lds(
                (const __attribute__((address_space(1))) unsigned*)(gsrc[i2] + k0),
                (__attribute__((address_space(3))) unsigned*)ldst[i2], 16, 0, 0);
        __syncthreads();

        #pragma unroll
        for (int kh = 0; kh < 2; ++kh) {
            short8 af[MI], bfr[4];
            #pragma unroll
            for (int i = 0; i < MI; ++i)
                af[i] = *(const short8*)(As + kh * TM * 32 + (wm + i * 16 + frow) * 32 + koff);
            #pragma unroll
            for (int j = 0; j < 4; ++j)
                bfr[j] = *(const short8*)(Bs + kh * 128 * 32 + (wn + j * 16 + frow) * 32 + koff);
            #pragma unroll
            for (int i = 0; i < MI; ++i)
                #pragma unroll
                for (int j = 0; j < 4; ++j)
                    acc[i][j] = __builtin_amdgcn_mfma_f32_16x16x32_bf16(af[i], bfr[j], acc[i][j], 0, 0, 0);
        }
        __syncthreads();
    }

    // epilogue: C/D layout col(n)=lane&15, row(m)=(lane>>4)*4+reg
    const int ecol = lane & 15, erow = (lane >> 4) * 4;
    const int zone = ROUTE ? (tileN >> 10) : 0;
    #pragma unroll
    for (int j = 0; j < 4; ++j) {
        int n = tileN + wn + j * 16 + ecol;
        float bv = BIAS ? bias[n] : 0.f;
        int nl = ROUTE ? (n & 1023) : n;
        #pragma unroll
        for (int i = 0; i < MI; ++i) {
            int mbase = tileM + wm + i * 16 + erow;
            #pragma unroll
            for (int r = 0; r < 4; ++r) {
                float val = acc[i][j][r] + bv;
                if (ACT == 1) val = 0.5f * val * (1.0f + erff(val * 0.70710678118654752f));
                int mrow = mbase + r;
                if (ROUTE) {
                    if (zone == 0) {
                        // 0.125 (1/sqrt(64)) * log2(e) folded so flash uses exp2 directly
                        ((unsigned short*)O0)[(size_t)mrow * 1024 + nl] = f2bf(val * 0.18033688011112042f);
                    } else if (zone == 1) {
                        ((unsigned short*)O1)[(size_t)mrow * 1024 + nl] = f2bf(val);
                    } else {
                        int bb = mrow >> 11, tt = mrow & 2047;
                        int hh = nl >> 6, dd = nl & 63;
                        ((unsigned short*)O2)[((size_t)((bb * 16 + hh) * 64 + dd)) * 2048 + tt] = f2bf(val);
                    }
                } else {
                    size_t idx = (size_t)mrow * N + n;
                    if (RES) val += resid[idx];
                    if (OBF16) ((unsigned short*)O0)[idx] = f2bf(val);
                    else       ((float*)O0)[idx] = val;
                }
            }
        }
    }
}

// ---------------- MFMA flash attention — 32x32 MFMA, 32q/wave, in-register softmax ----------
// (identical to previous round; resubmitted after infra-side container failure)
// q,k layout [b][t][h*64+d] bf16 (q pre-scaled 0.125*log2e); vT layout [b][h][d][t] bf16.
// Block = 4 waves x 32 q-rows = 128 q. KVBLK=64, K/V double-buffered via global_load_lds
// (linear dest + pre-swizzled source chunk^=(row&7)), one barrier per KV tile (R3 skeleton).
// S^T = mfma_32x32x16(K, Q): D col=lane&31=q, row=(reg&3)+8*(reg>>2)+4*(lane>>5)=s.
// Softmax max-free: P=exp2(S) in-place, l additive (rowsum: 32 adds + 1 shfl_xor 32).
// P -> PV A-operand ENTIRELY in registers: cvt_pk pairs + lane-half swap
// (shfl_xor(32)+select == permlane32_swap semantics). No P LDS round-trip.
// PV: mfma_32x32x16(P, V^T): O col=lane&31=d, row=q. Epilogue: 1/l broadcast via
// per-lane __shfl index (l lives at lane==q).
__global__ __launch_bounds__(256, 3) void flash_mfma_kernel(
        const unsigned short* __restrict__ q, const unsigned short* __restrict__ k,
        const unsigned short* __restrict__ vT, unsigned short* __restrict__ out) {
    __shared__ unsigned short KsA[64 * 64];
    __shared__ unsigned short VtA[64 * 64];
    __shared__ unsigned short KsB[64 * 64];
    __shared__ unsigned short VtB[64 * 64];

    const int tid  = threadIdx.x;
    const int w    = tid >> 6, lane = tid & 63;
    const int l31  = lane & 31, hi = lane >> 5;
    const int bh   = blockIdx.x;
    const int qt   = (gridDim.y - 1) - blockIdx.y;   // 0..15, big tiles first
    const int h = bh & (H_ - 1);
    const int b = bh >> 4;

    const size_t qkbase = (size_t)b * T_ * C_ + h * HD_;
    const size_t vbase  = (size_t)(b * H_ + h) * HD_ * T_;

    const int wq = qt * 128 + w * 32;          // wave q-base
    const int qg = wq + l31;                   // this lane's q row

    // Q B-frags: B[n=q=lane&31][k=d]: QB[ks] = q[qg][ks*16 + hi*8 .. +8]
    short8 QB[4];
    {
        const unsigned short* qp = q + qkbase + (size_t)qg * C_ + hi * 8;
        QB[0] = *(const short8*)(qp);
        QB[1] = *(const short8*)(qp + 16);
        QB[2] = *(const short8*)(qp + 32);
        QB[3] = *(const short8*)(qp + 48);
    }

    f32x16 O0, O1;
    #pragma unroll
    for (int i = 0; i < 16; ++i) { O0[i] = 0.f; O1[i] = 0.f; }
    float l_i = 0.f;

    const int r8 = lane >> 3, c7 = lane & 7;
    const int cswz = (c7 ^ r8) * 8;            // inverse-swizzled source chunk (shorts)
    const int rxA = l31 & 7;                   // row&7 key for KA/VB reads

    auto stageKV = [&](unsigned short* Ksb, unsigned short* Vtb, int tt) {
        const int s0_ = tt * 64;
        #pragma unroll
        for (int c = 0; c < 2; ++c) {
            const int row = w * 16 + c * 8 + r8;        // row&7 == r8
            const unsigned short* gk = k + qkbase + (size_t)(s0_ + row) * C_ + cswz;
            __builtin_amdgcn_global_load_lds(
                (const __attribute__((address_space(1))) unsigned*)gk,
                (__attribute__((address_space(3))) unsigned*)(Ksb + (w * 16 + c * 8) * 64), 16, 0, 0);
            const unsigned short* gv = vT + vbase + (size_t)row * T_ + s0_ + cswz;
            __builtin_amdgcn_global_load_lds(
                (const __attribute__((address_space(1))) unsigned*)gv,
                (__attribute__((address_space(3))) unsigned*)(Vtb + (w * 16 + c * 8) * 64), 16, 0, 0);
        }
    };

    auto computeTile = [&](const unsigned short* Ksb, const unsigned short* Vtb, int tt) {
        const int s0 = tt * 64;
        if (s0 > wq + 31) return;              // tile fully masked for this wave (wave-uniform)
        const bool diag = (s0 + 63 > wq);

        // ---- S^T: 2 frags 32x32 (s-rows sb*32.., q-cols); K-dim d=64 in 4 k-slots ----
        f32x16 S0, S1;
        #pragma unroll
        for (int i = 0; i < 16; ++i) { S0[i] = 0.f; S1[i] = 0.f; }
        {
            const unsigned short* kr0 = Ksb + l31 * 64;          // rows 0..31, row&7==rxA
            const unsigned short* kr1 = Ksb + (32 + l31) * 64;   // rows 32..63, same key
            #pragma unroll
            for (int ks = 0; ks < 4; ++ks) {
                short8 KA0 = *(const short8*)(kr0 + (((ks << 1) | hi) ^ rxA) * 8);
                short8 KA1 = *(const short8*)(kr1 + (((ks << 1) | hi) ^ rxA) * 8);
                S0 = __builtin_amdgcn_mfma_f32_32x32x16_bf16(KA0, QB[ks], S0, 0, 0, 0);
                S1 = __builtin_amdgcn_mfma_f32_32x32x16_bf16(KA1, QB[ks], S1, 0, 0, 0);
            }
        }

        // ---- P = exp2(S) in place, causal mask, rowsum ----
        float rs = 0.f;
        #pragma unroll
        for (int r = 0; r < 16; ++r) {
            float e0 = __builtin_amdgcn_exp2f(S0[r]);
            float e1 = __builtin_amdgcn_exp2f(S1[r]);
            if (diag) {
                int sg = s0 + (r & 3) + 8 * (r >> 2) + 4 * hi;
                e0 = (sg > qg) ? 0.f : e0;
                e1 = (sg + 32 > qg) ? 0.f : e1;
            }
            S0[r] = e0; S1[r] = e1;
            rs += e0 + e1;
        }
        rs += __shfl_xor(rs, 32, 64);          // combine lane-halves (same q, other s-rows)
        l_i += rs;

        // ---- P -> A-operand frags (in registers; lane-half swap via shfl+select) ----
        short8 PA[4];
        #pragma unroll
        for (int sb = 0; sb < 2; ++sb) {
            float p0  = sb ? S1[0]  : S0[0],  p1  = sb ? S1[1]  : S0[1];
            float p2  = sb ? S1[2]  : S0[2],  p3  = sb ? S1[3]  : S0[3];
            float p4  = sb ? S1[4]  : S0[4],  p5  = sb ? S1[5]  : S0[5];
            float p6  = sb ? S1[6]  : S0[6],  p7  = sb ? S1[7]  : S0[7];
            float p8  = sb ? S1[8]  : S0[8],  p9  = sb ? S1[9]  : S0[9];
            float p10 = sb ? S1[10] : S0[10], p11 = sb ? S1[11] : S0[11];
            float p12 = sb ? S1[12] : S0[12], p13 = sb ? S1[13] : S0[13];
            float p14 = sb ? S1[14] : S0[14], p15 = sb ? S1[15] : S0[15];
            unsigned xw0 = pk2bf(p0,  p1),  xw1 = pk2bf(p2,  p3);
            unsigned yw0 = pk2bf(p4,  p5),  yw1 = pk2bf(p6,  p7);
            unsigned xw2 = pk2bf(p8,  p9),  xw3 = pk2bf(p10, p11);
            unsigned yw2 = pk2bf(p12, p13), yw3 = pk2bf(p14, p15);
            unsigned xs0 = (unsigned)__shfl_xor((int)xw0, 32, 64);
            unsigned ys0 = (unsigned)__shfl_xor((int)yw0, 32, 64);
            unsigned xs1 = (unsigned)__shfl_xor((int)xw1, 32, 64);
            unsigned ys1 = (unsigned)__shfl_xor((int)yw1, 32, 64);
            unsigned xs2 = (unsigned)__shfl_xor((int)xw2, 32, 64);
            unsigned ys2 = (unsigned)__shfl_xor((int)yw2, 32, 64);
            unsigned xs3 = (unsigned)__shfl_xor((int)xw3, 32, 64);
            unsigned ys3 = (unsigned)__shfl_xor((int)yw3, 32, 64);
            uint4v w0, w1;
            w0[0] = hi ? ys0 : xw0;   // j0,j1
            w0[1] = hi ? ys1 : xw1;   // j2,j3
            w0[2] = hi ? yw0 : xs0;   // j4,j5
            w0[3] = hi ? yw1 : xs1;   // j6,j7
            w1[0] = hi ? ys2 : xw2;
            w1[1] = hi ? ys3 : xw3;
            w1[2] = hi ? yw2 : xs2;
            w1[3] = hi ? yw3 : xs3;
            PA[sb * 2 + 0] = __builtin_bit_cast(short8, w0);
            PA[sb * 2 + 1] = __builtin_bit_cast(short8, w1);
        }

        // ---- O += P.V (B[n=d=lane&31][k=s]) ----
        __builtin_amdgcn_s_setprio(1);
        {
            const unsigned short* vr0 = Vtb + l31 * 64;          // d 0..31
            const unsigned short* vr1 = Vtb + (32 + l31) * 64;   // d 32..63
            #pragma unroll
            for (int ks = 0; ks < 4; ++ks) {
                short8 VB0 = *(const short8*)(vr0 + (((ks << 1) | hi) ^ rxA) * 8);
                short8 VB1 = *(const short8*)(vr1 + (((ks << 1) | hi) ^ rxA) * 8);
                O0 = __builtin_amdgcn_mfma_f32_32x32x16_bf16(PA[ks], VB0, O0, 0, 0, 0);
                O1 = __builtin_amdgcn_mfma_f32_32x32x16_bf16(PA[ks], VB1, O1, 0, 0, 0);
            }
        }
        __builtin_amdgcn_s_setprio(0);
    };

    // pipelined loop: issue stage(t+1) -> compute(t) -> barrier (drains the prefetch)
    const int NT = 2 * qt + 2;
    stageKV(KsA, VtA, 0);
    __syncthreads();
    int tt = 0;
    for (;;) {
        if (tt + 1 < NT) stageKV(KsB, VtB, tt + 1);
        computeTile(KsA, VtA, tt);
        __syncthreads();
        ++tt; if (tt >= NT) break;
        if (tt + 1 < NT) stageKV(KsA, VtA, tt + 1);
        computeTile(KsB, VtB, tt);
        __syncthreads();
        ++tt; if (tt >= NT) break;
    }

    // ---- epilogue: divide by l (per-lane-index shfl broadcast), store bf16 ----
    float inv = 1.0f / l_i;                    // valid for q = wq + l31 (both halves)
    #pragma unroll
    for (int r = 0; r < 16; ++r) {
        int ql = (r & 3) + 8 * (r >> 2) + 4 * hi;   // O row (q within wave)
        float invr = __shfl(inv, ql, 64);           // lane ql holds l for q=wq+ql
        int row = wq + ql;
        size_t obase = ((size_t)(b * T_ + row)) * C_ + h * HD_ + l31;
        out[obase]      = f2bf(O0[r] * invr);
        out[obase + 32] = f2bf(O1[r] * invr);
    }
}

extern "C" void kernel_launch(void* const* d_in, const int* in_sizes, int n_in,
                              void* d_out, int out_size, void* d_ws, size_t ws_size,
                              hipStream_t stream) {
    const float* target = (const float*)d_in[0];
    const float* wq     = (const float*)d_in[1];
    const float* wk     = (const float*)d_in[2];
    const float* wv     = (const float*)d_in[3];
    const float* w_proj = (const float*)d_in[4];
    const float* b_proj = (const float*)d_in[5];
    const float* w1     = (const float*)d_in[6];
    const float* b1     = (const float*)d_in[7];
    const float* w2     = (const float*)d_in[8];
    const float* b2     = (const float*)d_in[9];
    const float* g1     = (const float*)d_in[10];
    const float* g2     = (const float*)d_in[11];
    float* out = (float*)d_out;

    char* ws = (char*)d_ws;
    const size_t MB = 1u << 20;
    unsigned short* xn = (unsigned short*)(ws);            // 8 MB; attn_out later
    unsigned short* q  = (unsigned short*)(ws + 8 * MB);   // 8 MB; y later
    unsigned short* k  = (unsigned short*)(ws + 16 * MB);  // 8 MB; h later (16MB)
    unsigned short* vt = (unsigned short*)(ws + 24 * MB);  // 8 MB  [b][h][d][t]
    float*          x2 = (float*)(ws + 32 * MB);           // 16 MB fp32
    unsigned short* wb = (unsigned short*)(ws + 48 * MB);  // 16 MB bf16 weights
    unsigned short* y  = q;
    unsigned short* hb = k;

    unsigned short* wqkv_b = wb;                  // [3072][1024] concat
    unsigned short* wp_b   = wb + 3145728u;
    unsigned short* w1_b   = wb + 4194304u;
    unsigned short* w2_b   = wb + 6291456u;

    const int M = B_ * T_;  // 4096

    // weights->bf16 + rmsnorm1 in one dispatch
    prep_kernel<<<12288, 256, 0, stream>>>(wq, wk, wv, w_proj, w1, w2, wb, target, g1, xn);

    // QKV fused: [4096,1024] x [3072,1024]^T; route q(scaled)/k/vT by n-zone
    mfma_gemm<128, 0, false, false, true, 1><<<dim3(24, M / 128), 256, 0, stream>>>(
        xn, wqkv_b, nullptr, nullptr, q, k, vt, M, 3072, C_);

    // flash: 4 waves x 32q = 128 q-rows per block -> grid 32 x 16 = 512 blocks
    flash_mfma_kernel<<<dim3(B_ * H_, T_ / 128), 256, 0, stream>>>(q, k, vt, xn);

    // proj: TM=64 -> 512 blocks, 2/CU
    mfma_gemm<64, 0, true, true, false, 0><<<dim3(C_ / 128, M / 64), 256, 0, stream>>>(
        xn, wp_b, b_proj, target, x2, nullptr, nullptr, M, C_, C_);

    rmsnorm_bf16_kernel<<<M, 256, 0, stream>>>(x2, g2, y);

    // FFN1: TM=64 -> 1024 blocks (R3 best-known config)
    mfma_gemm<64, 1, true, false, true, 0><<<dim3(FF_ / 128, M / 64), 256, 0, stream>>>(
        y, w1_b, b1, nullptr, hb, nullptr, nullptr, M, FF_, C_);

    // FFN2: TM=64 -> 512 blocks
    mfma_gemm<64, 0, true, true, false, 0><<<dim3(C_ / 128, M / 64), 256, 0, stream>>>(
        hb, w2_b, b2, x2, out, nullptr, nullptr, M, C_, FF_);
}

// Round 9
// 270.925 us; speedup vs baseline: 1.0602x; 1.0602x over previous
//
#include <hip/hip_runtime.h>
#include <math.h>

#define B_  2
#define T_  2048
#define C_  1024
#define H_  16
#define HD_ 64
#define FF_ 2048
#define EPS_ 1.1920929e-07f

typedef __attribute__((ext_vector_type(8))) short short8;
typedef __attribute__((ext_vector_type(4))) float f32x4;
typedef __attribute__((ext_vector_type(2))) __bf16 bf16x2v;

__device__ __forceinline__ unsigned short f2bf(float f) {
    unsigned u = __float_as_uint(f);
    u += 0x7fffu + ((u >> 16) & 1u);          // round-to-nearest-even
    return (unsigned short)(u >> 16);
}
__device__ __forceinline__ float bf2f(unsigned short u) {
    return __uint_as_float(((unsigned)u) << 16);
}
// packed pair convert -> v_cvt_pk_bf16_f32 (RNE, one instr per 2 floats)
__device__ __forceinline__ unsigned pk2bf(float a, float b) {
    bf16x2v v;
    v[0] = (__bf16)a;
    v[1] = (__bf16)b;
    return __builtin_bit_cast(unsigned, v);
}

// ---------------- prep: weight fp32->bf16 convert + rmsnorm1, one dispatch ----------------
__global__ void prep_kernel(const float* __restrict__ wq, const float* __restrict__ wk,
                            const float* __restrict__ wv, const float* __restrict__ wp,
                            const float* __restrict__ w1, const float* __restrict__ w2,
                            unsigned short* __restrict__ wb,
                            const float* __restrict__ x, const float* __restrict__ g,
                            unsigned short* __restrict__ y) {
    int tid = threadIdx.x;
    if (blockIdx.x < 8192) {
        size_t i = ((size_t)blockIdx.x * 256 + tid) * 4;
        const float* src; size_t off = i;
        if      (i < 1048576u)  { src = wq; }
        else if (i < 2097152u)  { src = wk; off = i - 1048576u; }
        else if (i < 3145728u)  { src = wv; off = i - 2097152u; }
        else if (i < 4194304u)  { src = wp; off = i - 3145728u; }
        else if (i < 6291456u)  { src = w1; off = i - 4194304u; }
        else                    { src = w2; off = i - 6291456u; }
        float4 v4 = *(const float4*)(src + off);
        ushort4 o4;
        o4.x = f2bf(v4.x); o4.y = f2bf(v4.y); o4.z = f2bf(v4.z); o4.w = f2bf(v4.w);
        *(ushort4*)(wb + i) = o4;
    } else {
        int row = blockIdx.x - 8192;
        const float4* xr = (const float4*)(x + (size_t)row * C_);
        float4 xv = xr[tid];
        float ss = xv.x * xv.x + xv.y * xv.y + xv.z * xv.z + xv.w * xv.w;
        #pragma unroll
        for (int m = 32; m >= 1; m >>= 1) ss += __shfl_xor(ss, m, 64);
        __shared__ float sred[4];
        if ((tid & 63) == 0) sred[tid >> 6] = ss;
        __syncthreads();
        float tot = sred[0] + sred[1] + sred[2] + sred[3];
        float r = rsqrtf(tot * (1.0f / C_) + EPS_);
        float4 gv = ((const float4*)g)[tid];
        ushort4 o;
        o.x = f2bf(xv.x * r * gv.x);
        o.y = f2bf(xv.y * r * gv.y);
        o.z = f2bf(xv.z * r * gv.z);
        o.w = f2bf(xv.w * r * gv.w);
        *((ushort4*)(y + (size_t)row * C_) + tid) = o;
    }
}

// ---------------- RMSNorm (fp32 in, bf16 out) ----------------
__global__ void rmsnorm_bf16_kernel(const float* __restrict__ x, const float* __restrict__ g,
                                    unsigned short* __restrict__ y) {
    int row = blockIdx.x;
    int tid = threadIdx.x;
    const float4* xr = (const float4*)(x + (size_t)row * C_);
    float4 xv = xr[tid];
    float ss = xv.x * xv.x + xv.y * xv.y + xv.z * xv.z + xv.w * xv.w;
    #pragma unroll
    for (int m = 32; m >= 1; m >>= 1) ss += __shfl_xor(ss, m, 64);
    __shared__ float sred[4];
    if ((tid & 63) == 0) sred[tid >> 6] = ss;
    __syncthreads();
    float tot = sred[0] + sred[1] + sred[2] + sred[3];
    float r = rsqrtf(tot * (1.0f / C_) + EPS_);
    float4 gv = ((const float4*)g)[tid];
    ushort4 o;
    o.x = f2bf(xv.x * r * gv.x);
    o.y = f2bf(xv.y * r * gv.y);
    o.z = f2bf(xv.z * r * gv.z);
    o.w = f2bf(xv.w * r * gv.w);
    *((ushort4*)(y + (size_t)row * C_) + tid) = o;
}

// ---------------- bf16 MFMA GEMM, TM x 128 tile, BK=64 ----------------
// LDS layout: two BK=32 sub-tiles [kh][rows][32] for A and B.
// ROUTE==1 (QKV, N=3072): n-zone 0 -> q (x0.125*log2e), zone 1 -> k, zone 2 -> vT.
// T1 XCD-chunked blockIdx swizzle: linear wgid round-robins across the 8 per-XCD
// L2s, so blocks sharing an A-panel land on different XCDs and each re-fetches it
// (measured: QKV FETCH 36MB vs 14MB ideal). Chunked remap gives each XCD a
// contiguous tileM range -> A-panels L2-resident. Requires nwg%8==0 (all our
// grids: 768/512/1024/512). Bijective.
template <int TM, int ACT, bool BIAS, bool RES, bool OBF16, int ROUTE>
__global__ __launch_bounds__(256) void mfma_gemm(
        const unsigned short* __restrict__ A, const unsigned short* __restrict__ W,
        const float* __restrict__ bias, const float* __restrict__ resid,
        void* __restrict__ O0, void* __restrict__ O1, void* __restrict__ O2,
        int M, int N, int K) {
    constexpr int ACH = TM / 8;           // A chunks (TM rows * 64 k * 2B / 1KB)
    constexpr int NCH = (ACH + 16) / 4;   // chunks per wave
    constexpr int MI  = TM / 32;          // m-frags per wave
    __shared__ short As[2 * TM * 32];
    __shared__ short Bs[2 * 128 * 32];
    const int tid  = threadIdx.x;
    const int w    = tid >> 6, lane = tid & 63;

    // XCD-chunked swizzle (nwg % 8 == 0 for every launch in this file)
    const int gx  = gridDim.x;
    const int nwg = gx * gridDim.y;
    const int wg  = blockIdx.y * gx + blockIdx.x;
    const int swz = (wg & 7) * (nwg >> 3) + (wg >> 3);
    const int tileN = (swz % gx) * 128, tileM = (swz / gx) * TM;

    const unsigned short* gsrc[NCH];
    short* ldst[NCH];
    #pragma unroll
    for (int i2 = 0; i2 < NCH; ++i2) {
        int c = w * NCH + i2;
        if (c < ACH) {
            int kh = c / (ACH / 2), lc = c % (ACH / 2);
            gsrc[i2] = A + (size_t)(tileM + lc * 16 + (lane >> 2)) * K + kh * 32 + (lane & 3) * 8;
            ldst[i2] = As + c * 512;
        } else {
            int c2 = c - ACH;
            int kh = c2 >> 3, lc = c2 & 7;
            gsrc[i2] = W + (size_t)(tileN + lc * 16 + (lane >> 2)) * K + kh * 32 + (lane & 3) * 8;
            ldst[i2] = Bs + c2 * 512;
        }
    }

    f32x4 acc[MI][4];
    const f32x4 zed = {0.f, 0.f, 0.f, 0.f};
    #pragma unroll
    for (int i = 0; i < MI; ++i)
        #pragma unroll
        for (int j = 0; j < 4; ++j) acc[i][j] = zed;

    const int wm = (w >> 1) * (TM / 2), wn = (w & 1) * 64;
    const int frow = lane & 15, koff = (lane >> 4) * 8;

    for (int k0 = 0; k0 < K; k0 += 64) {
        #pragma unroll
        for (int i2 = 0; i2 < NCH; ++i2)
            __builtin_amdgcn_global_load_lds(
                (const __attribute__((address_space(1))) unsigned*)(gsrc[i2] + k0),
                (__attribute__((address_space(3))) unsigned*)ldst[i2], 16, 0, 0);
        __syncthreads();

        #pragma unroll
        for (int kh = 0; kh < 2; ++kh) {
            short8 af[MI], bfr[4];
            #pragma unroll
            for (int i = 0; i < MI; ++i)
                af[i] = *(const short8*)(As + kh * TM * 32 + (wm + i * 16 + frow) * 32 + koff);
            #pragma unroll
            for (int j = 0; j < 4; ++j)
                bfr[j] = *(const short8*)(Bs + kh * 128 * 32 + (wn + j * 16 + frow) * 32 + koff);
            #pragma unroll
            for (int i = 0; i < MI; ++i)
                #pragma unroll
                for (int j = 0; j < 4; ++j)
                    acc[i][j] = __builtin_amdgcn_mfma_f32_16x16x32_bf16(af[i], bfr[j], acc[i][j], 0, 0, 0);
        }
        __syncthreads();
    }

    // epilogue: C/D layout col(n)=lane&15, row(m)=(lane>>4)*4+reg
    const int ecol = lane & 15, erow = (lane >> 4) * 4;
    const int zone = ROUTE ? (tileN >> 10) : 0;
    #pragma unroll
    for (int j = 0; j < 4; ++j) {
        int n = tileN + wn + j * 16 + ecol;
        float bv = BIAS ? bias[n] : 0.f;
        int nl = ROUTE ? (n & 1023) : n;
        #pragma unroll
        for (int i = 0; i < MI; ++i) {
            int mbase = tileM + wm + i * 16 + erow;
            #pragma unroll
            for (int r = 0; r < 4; ++r) {
                float val = acc[i][j][r] + bv;
                if (ACT == 1) val = 0.5f * val * (1.0f + erff(val * 0.70710678118654752f));
                int mrow = mbase + r;
                if (ROUTE) {
                    if (zone == 0) {
                        // 0.125 (1/sqrt(64)) * log2(e) folded so flash uses exp2 directly
                        ((unsigned short*)O0)[(size_t)mrow * 1024 + nl] = f2bf(val * 0.18033688011112042f);
                    } else if (zone == 1) {
                        ((unsigned short*)O1)[(size_t)mrow * 1024 + nl] = f2bf(val);
                    } else {
                        int bb = mrow >> 11, tt = mrow & 2047;
                        int hh = nl >> 6, dd = nl & 63;
                        ((unsigned short*)O2)[((size_t)((bb * 16 + hh) * 64 + dd)) * 2048 + tt] = f2bf(val);
                    }
                } else {
                    size_t idx = (size_t)mrow * N + n;
                    if (RES) val += resid[idx];
                    if (OBF16) ((unsigned short*)O0)[idx] = f2bf(val);
                    else       ((float*)O0)[idx] = val;
                }
            }
        }
    }
}

// ---------------- MFMA flash attention (R3 structure — best measured, restored) ----------
// q,k layout [b][t][h*64+d] bf16 (q pre-scaled 0.125*log2e); vT layout [b][h][d][t] bf16.
// S^T = K.Q^T. Max-free softmax: P = exp2(S), l additive. K/V via width-16
// global_load_lds, linear [64][64] LDS, double-buffered, both-sides chunk^=(row&7)
// swizzle; one barrier per KV tile; single per-wave Ps buffer (DS in-order);
// v_cvt_pk_bf16_f32 packing; PV0 under sb1 round-trip; setprio around PV.
// Default block->XCD mapping is already optimal here (same-(b,h) q-tiles share
// wgid mod 8 -> same XCD L2 holds that head's K/V) — no swizzle.
__global__ __launch_bounds__(256, 4) void flash_mfma_kernel(
        const unsigned short* __restrict__ q, const unsigned short* __restrict__ k,
        const unsigned short* __restrict__ vT, unsigned short* __restrict__ out) {
    __shared__ unsigned short KsA[64 * 64];
    __shared__ unsigned short VtA[64 * 64];
    __shared__ unsigned short KsB[64 * 64];
    __shared__ unsigned short VtB[64 * 64];
    __shared__ unsigned short Ps[4 * 16 * 40];     // per-wave [q][s] stride 40, reused per sb

    const int tid  = threadIdx.x;
    const int w    = tid >> 6, lane = tid & 63;
    const int quad = lane >> 4, l15 = lane & 15;
    const int bh = blockIdx.x;
    const int qt = (gridDim.y - 1) - blockIdx.y;   // big tiles first
    const int h = bh & (H_ - 1);
    const int b = bh >> 4;

    const size_t qkbase = (size_t)b * T_ * C_ + h * HD_;
    const size_t vbase  = (size_t)(b * H_ + h) * HD_ * T_;

    short8 QB[2];
    {
        const unsigned short* qp = q + qkbase + (size_t)(qt * 64 + w * 16 + l15) * C_;
        QB[0] = *(const short8*)(qp + quad * 8);
        QB[1] = *(const short8*)(qp + 32 + quad * 8);
    }

    f32x4 O[4];
    const f32x4 zed = {0.f, 0.f, 0.f, 0.f};
    #pragma unroll
    for (int dt = 0; dt < 4; ++dt) O[dt] = zed;
    float l_i = 0.f;

    const int qg = qt * 64 + w * 16 + l15;
    const int psoff = w * 640 + l15 * 40;
    const int r8 = lane >> 3, c7 = lane & 7;
    const int cswz = (c7 ^ r8) * 8;
    const int swz15 = (l15 & 7);
    const int kc = (quad ^ swz15) * 8;

    auto stageKV = [&](unsigned short* Ksb, unsigned short* Vtb, int st_) {
        const int s0_ = st_ * 64;
        #pragma unroll
        for (int c = 0; c < 2; ++c) {
            const int row = w * 16 + c * 8 + r8;
            const unsigned short* gk = k + qkbase + (size_t)(s0_ + row) * C_ + cswz;
            __builtin_amdgcn_global_load_lds(
                (const __attribute__((address_space(1))) unsigned*)gk,
                (__attribute__((address_space(3))) unsigned*)(Ksb + (w * 16 + c * 8) * 64), 16, 0, 0);
            const unsigned short* gv = vT + vbase + (size_t)row * T_ + s0_ + cswz;
            __builtin_amdgcn_global_load_lds(
                (const __attribute__((address_space(1))) unsigned*)gv,
                (__attribute__((address_space(3))) unsigned*)(Vtb + (w * 16 + c * 8) * 64), 16, 0, 0);
        }
    };

    auto computeTile = [&](const unsigned short* Ksb, const unsigned short* Vtb, int st_) {
        const bool diag = (st_ == qt);
        const int s0_ = st_ * 64;
        f32x4 Sacc[4];
        #pragma unroll
        for (int i = 0; i < 4; ++i) {
            const unsigned short* kr = Ksb + (i * 16 + l15) * 64;
            short8 KA0 = *(const short8*)(kr + kc);
            short8 KA1 = *(const short8*)(kr + (kc ^ 32));
            Sacc[i] = __builtin_amdgcn_mfma_f32_16x16x32_bf16(KA0, QB[0], zed, 0, 0, 0);
            Sacc[i] = __builtin_amdgcn_mfma_f32_16x16x32_bf16(KA1, QB[1], Sacc[i], 0, 0, 0);
        }
        float vals[16];
        #pragma unroll
        for (int i = 0; i < 4; ++i)
            #pragma unroll
            for (int r = 0; r < 4; ++r) {
                float e = __builtin_amdgcn_exp2f(Sacc[i][r]);
                if (diag) {
                    int sg = s0_ + i * 16 + quad * 4 + r;
                    e = (sg > qg) ? 0.f : e;
                }
                vals[i * 4 + r] = e;
            }
        float rs = 0.f;
        #pragma unroll
        for (int i = 0; i < 16; ++i) rs += vals[i];
        rs += __shfl_xor(rs, 16, 64);
        rs += __shfl_xor(rs, 32, 64);
        l_i += rs;

        uint2 p0, p1;
        p0.x = pk2bf(vals[0], vals[1]);  p0.y = pk2bf(vals[2], vals[3]);
        p1.x = pk2bf(vals[4], vals[5]);  p1.y = pk2bf(vals[6], vals[7]);
        *(uint2*)&Ps[psoff + quad * 4]      = p0;
        *(uint2*)&Ps[psoff + 16 + quad * 4] = p1;
        short8 PA0 = *(const short8*)&Ps[psoff + quad * 8];

        uint2 p2, p3;
        p2.x = pk2bf(vals[8], vals[9]);   p2.y = pk2bf(vals[10], vals[11]);
        p3.x = pk2bf(vals[12], vals[13]); p3.y = pk2bf(vals[14], vals[15]);
        *(uint2*)&Ps[psoff + quad * 4]      = p2;
        *(uint2*)&Ps[psoff + 16 + quad * 4] = p3;

        __builtin_amdgcn_s_setprio(1);
        #pragma unroll
        for (int dt = 0; dt < 4; ++dt) {
            const unsigned short* vr = Vtb + (16 * dt + l15) * 64;
            short8 VB0 = *(const short8*)(vr + ((quad ^ swz15) * 8));
            O[dt] = __builtin_amdgcn_mfma_f32_16x16x32_bf16(PA0, VB0, O[dt], 0, 0, 0);
        }
        short8 PA1 = *(const short8*)&Ps[psoff + quad * 8];
        #pragma unroll
        for (int dt = 0; dt < 4; ++dt) {
            const unsigned short* vr = Vtb + (16 * dt + l15) * 64;
            short8 VB1 = *(const short8*)(vr + (((4 + quad) ^ swz15) * 8));
            O[dt] = __builtin_amdgcn_mfma_f32_16x16x32_bf16(PA1, VB1, O[dt], 0, 0, 0);
        }
        __builtin_amdgcn_s_setprio(0);
    };

    stageKV(KsA, VtA, 0);
    __syncthreads();
    int st = 0;
    for (;;) {
        if (st + 1 <= qt) stageKV(KsB, VtB, st + 1);
        computeTile(KsA, VtA, st);
        __syncthreads();
        ++st; if (st > qt) break;
        if (st + 1 <= qt) stageKV(KsA, VtA, st + 1);
        computeTile(KsB, VtB, st);
        __syncthreads();
        ++st; if (st > qt) break;
    }

    f32x4 inv;
    #pragma unroll
    for (int r = 0; r < 4; ++r) inv[r] = 1.0f / __shfl(l_i, quad * 4 + r, 64);
    #pragma unroll
    for (int dt = 0; dt < 4; ++dt)
        #pragma unroll
        for (int r = 0; r < 4; ++r) {
            int row = qt * 64 + w * 16 + quad * 4 + r;
            int col = h * HD_ + dt * 16 + l15;
            out[((size_t)(b * T_ + row)) * C_ + col] = f2bf(O[dt][r] * inv[r]);
        }
}

extern "C" void kernel_launch(void* const* d_in, const int* in_sizes, int n_in,
                              void* d_out, int out_size, void* d_ws, size_t ws_size,
                              hipStream_t stream) {
    const float* target = (const float*)d_in[0];
    const float* wq     = (const float*)d_in[1];
    const float* wk     = (const float*)d_in[2];
    const float* wv     = (const float*)d_in[3];
    const float* w_proj = (const float*)d_in[4];
    const float* b_proj = (const float*)d_in[5];
    const float* w1     = (const float*)d_in[6];
    const float* b1     = (const float*)d_in[7];
    const float* w2     = (const float*)d_in[8];
    const float* b2     = (const float*)d_in[9];
    const float* g1     = (const float*)d_in[10];
    const float* g2     = (const float*)d_in[11];
    float* out = (float*)d_out;

    char* ws = (char*)d_ws;
    const size_t MB = 1u << 20;
    unsigned short* xn = (unsigned short*)(ws);            // 8 MB; attn_out later
    unsigned short* q  = (unsigned short*)(ws + 8 * MB);   // 8 MB; y later
    unsigned short* k  = (unsigned short*)(ws + 16 * MB);  // 8 MB; h later (16MB)
    unsigned short* vt = (unsigned short*)(ws + 24 * MB);  // 8 MB  [b][h][d][t]
    float*          x2 = (float*)(ws + 32 * MB);           // 16 MB fp32
    unsigned short* wb = (unsigned short*)(ws + 48 * MB);  // 16 MB bf16 weights
    unsigned short* y  = q;
    unsigned short* hb = k;

    unsigned short* wqkv_b = wb;                  // [3072][1024] concat
    unsigned short* wp_b   = wb + 3145728u;
    unsigned short* w1_b   = wb + 4194304u;
    unsigned short* w2_b   = wb + 6291456u;

    const int M = B_ * T_;  // 4096

    // weights->bf16 + rmsnorm1 in one dispatch
    prep_kernel<<<12288, 256, 0, stream>>>(wq, wk, wv, w_proj, w1, w2, wb, target, g1, xn);

    // QKV fused: [4096,1024] x [3072,1024]^T; route q(scaled)/k/vT by n-zone
    mfma_gemm<128, 0, false, false, true, 1><<<dim3(24, M / 128), 256, 0, stream>>>(
        xn, wqkv_b, nullptr, nullptr, q, k, vt, M, 3072, C_);

    flash_mfma_kernel<<<dim3(B_ * H_, T_ / 64), 256, 0, stream>>>(q, k, vt, xn);

    // proj: TM=64 -> 512 blocks, 2/CU
    mfma_gemm<64, 0, true, true, false, 0><<<dim3(C_ / 128, M / 64), 256, 0, stream>>>(
        xn, wp_b, b_proj, target, x2, nullptr, nullptr, M, C_, C_);

    rmsnorm_bf16_kernel<<<M, 256, 0, stream>>>(x2, g2, y);

    // FFN1: TM=64 -> 1024 blocks (R3 best-known config)
    mfma_gemm<64, 1, true, false, true, 0><<<dim3(FF_ / 128, M / 64), 256, 0, stream>>>(
        y, w1_b, b1, nullptr, hb, nullptr, nullptr, M, FF_, C_);

    // FFN2: TM=64 -> 512 blocks
    mfma_gemm<64, 0, true, true, false, 0><<<dim3(C_ / 128, M / 64), 256, 0, stream>>>(
        hb, w2_b, b2, x2, out, nullptr, nullptr, M, C_, FF_);
}